// Round 8
// baseline (213.426 us; speedup 1.0000x reference)
//
#include <hip/hip_runtime.h>
#include <stdint.h>

// ---------------- constants ----------------
#define DIM   768
#define NTOK  196
#define TT    8
#define MROWS 25088      // 3136 * 8
#define HEADS 12
#define NKT   12         // 768 / 64 K-tiles

typedef __bf16 bf16x8 __attribute__((ext_vector_type(8)));
typedef float  f32x4  __attribute__((ext_vector_type(4)));
typedef unsigned short u16x4 __attribute__((ext_vector_type(4)));
typedef unsigned short u16x8 __attribute__((ext_vector_type(8)));

typedef __attribute__((address_space(1))) const void GAS;
typedef __attribute__((address_space(3))) void LAS;

__device__ inline unsigned short f2bf(float f) {
  uint32_t u = __builtin_bit_cast(uint32_t, f);
  u += 0x7FFFu + ((u >> 16) & 1u);          // RNE
  return (unsigned short)(u >> 16);
}
__device__ inline float bf2f(unsigned short s) {
  uint32_t u = ((uint32_t)s) << 16;
  return __builtin_bit_cast(float, u);
}
__device__ inline void gl_lds16(const unsigned short* g, unsigned short* l) {
  __builtin_amdgcn_global_load_lds((GAS*)g, (LAS*)l, 16, 0, 0);
}
__device__ inline int xcd_swz(int orig, int nwg) {   // bijective (m204)
  int xcd = orig & 7, loc = orig >> 3;
  int q = nwg >> 3, r = nwg & 7;
  int base = (xcd < r) ? xcd * (q + 1) : r * (q + 1) + (xcd - r) * q;
  return base + loc;
}

#define WAITV(n) asm volatile("s_waitcnt vmcnt(" #n ")" ::: "memory")
#define CFENCE   asm volatile("" ::: "memory")

// ---------------- weight fp32 -> bf16 convert ----------------
__global__ void wprep_kernel(const float* __restrict__ wq,
                             const float* __restrict__ wkv,
                             const float* __restrict__ wproj,
                             unsigned short* __restrict__ out) {
  int idx4 = blockIdx.x * blockDim.x + threadIdx.x;
  const int total4 = 2359296 / 4;
  if (idx4 >= total4) return;
  int e = idx4 * 4;
  const float* src; int off;
  if (e < 589824)        { src = wq;    off = e; }
  else if (e < 1769472)  { src = wkv;   off = e - 589824; }
  else                   { src = wproj; off = e - 1769472; }
  f32x4 v = *reinterpret_cast<const f32x4*>(&src[off]);
  u16x4 o;
  o[0] = f2bf(v[0]); o[1] = f2bf(v[1]); o[2] = f2bf(v[2]); o[3] = f2bf(v[3]);
  *reinterpret_cast<u16x4*>(&out[e]) = o;
}

// ---------------- CLS row copy (exact fp32) ----------------
__global__ void cls_kernel(const float* __restrict__ sx, float* __restrict__ out) {
  int i4 = blockIdx.x * blockDim.x + threadIdx.x;
  if (i4 < (128 * 768) / 4)
    reinterpret_cast<f32x4*>(out)[i4] = reinterpret_cast<const f32x4*>(sx)[i4];
}

// ---------------- A prep: gather + time_pos + fp32->bf16 -------------------
// ybase + blockIdx.y selects stream: 0 = s_x->dstS (clip), 1 = t_x->dstT (vmae)
__global__ __launch_bounds__(256)
void aprep2_kernel(const float* __restrict__ s_x, const float* __restrict__ t_x,
                   const float* __restrict__ clip, const float* __restrict__ vmae,
                   unsigned short* __restrict__ dstS, unsigned short* __restrict__ dstT,
                   int ybase) {
  int idx = blockIdx.x * blockDim.x + threadIdx.x;      // one per 8 elems
  const int total = MROWS * (DIM / 8);
  if (idx >= total) return;
  int m  = idx / 96;
  int c8 = (idx - m * 96) * 8;
  int bn = m >> 3, t = m & 7;
  int b  = bn / NTOK, n = bn - b * NTOK;
  const float* src; const float* tp; unsigned short* dst; int srow;
  if ((int)blockIdx.y + ybase == 0) {
    srow = (1 + n) * 128 + b * 8 + t; src = s_x; tp = clip; dst = dstS;
  } else {
    srow = b * (TT * NTOK) + t * NTOK + n; src = t_x; tp = vmae; dst = dstT;
  }
  const float* sp = &src[srow * DIM + c8];
  const float* pp = &tp[t * DIM + c8];
  f32x4 a0 = reinterpret_cast<const f32x4*>(sp)[0];
  f32x4 a1 = reinterpret_cast<const f32x4*>(sp)[1];
  f32x4 p0 = reinterpret_cast<const f32x4*>(pp)[0];
  f32x4 p1 = reinterpret_cast<const f32x4*>(pp)[1];
  a0 += p0; a1 += p1;
  u16x8 o;
  o[0] = f2bf(a0[0]); o[1] = f2bf(a0[1]); o[2] = f2bf(a0[2]); o[3] = f2bf(a0[3]);
  o[4] = f2bf(a1[0]); o[5] = f2bf(a1[1]); o[6] = f2bf(a1[2]); o[7] = f2bf(a1[3]);
  *reinterpret_cast<u16x8*>(&dst[m * DIM + c8]) = o;
}

// ---------------- QKV GEMM: ring-3 counted-vmcnt, 16x16 MFMA ---------------
// BM=256, BN=128, BK=64, 8 waves in 4m x 2n grid (per-wave 64x64).
// LDS traffic/K-tile = 2x32KB(A) + 4x16KB(B) = 128 KB (was 160 at 2m x 4n).
// Inner body: stage(kt+2) issue -> read all 16 frags -> 32 MFMAs, NO
// sched_barrier inside (let compiler pipeline ds_read under MFMA).
__global__ __launch_bounds__(512)
void gemm8(const unsigned short* __restrict__ As,
           const unsigned short* __restrict__ At,
           const unsigned short* __restrict__ W0,
           const unsigned short* __restrict__ W1,
           const float* __restrict__ b0,
           const float* __restrict__ b1,
           unsigned short* __restrict__ out0,
           unsigned short* __restrict__ out1,
           int bid0) {
  __shared__ unsigned short SB[3 * 24576];

  const int tid  = threadIdx.x;
  const int lane = tid & 63;
  const int w    = tid >> 6;
  const int wm   = w & 3;                    // 0..3: 64-row slice
  const int wn   = w >> 2;                   // 0..1: 64-col slice

  int bid = xcd_swz(blockIdx.x, gridDim.x) + bid0;

  const unsigned short *Ag, *Wg;
  const float* bias;
  unsigned short* ob;
  int rt, ct, Ncols;
  float scale = 1.0f;
  if (bid < 588) { rt = bid / 6;  ct = bid % 6;  Ag = As; Wg = W0; bias = b0; ob = out0; Ncols = 768;  scale = 0.125f; }
  else { int b2 = bid - 588; rt = b2 / 12; ct = b2 % 12; Ag = At; Wg = W1; bias = b1; ob = out1; Ncols = 1536; }
  const int m0 = rt * 256;
  const int n0 = ct * 128;

  auto stageA = [&](int kt) {
    const int kb = kt * 64;
    unsigned short* dst = &SB[(kt % 3) * 24576];
    #pragma unroll
    for (int rnd = 0; rnd < 4; ++rnd) {
      int s    = rnd * 8 + w;
      int srow = s * 8 + (lane >> 3);
      int scol = ((lane & 7) * 8) ^ ((srow & 7) << 3);
      gl_lds16(&Ag[(size_t)(m0 + srow) * 768 + kb + scol], dst + s * 512);
    }
  };
  auto stageB = [&](int kt) {
    const int kb = kt * 64;
    unsigned short* dst = &SB[(kt % 3) * 24576 + 16384];
    #pragma unroll
    for (int rnd = 0; rnd < 2; ++rnd) {
      int s    = rnd * 8 + w;
      int srow = s * 8 + (lane >> 3);
      int scol = ((lane & 7) * 8) ^ ((srow & 7) << 3);
      gl_lds16(&Wg[(size_t)(n0 + srow) * 768 + kb + scol], dst + s * 512);
    }
  };

  f32x4 acc[4][4] = {};

  stageA(0); stageB(0);
  stageA(1); stageB(1);

  for (int kt = 0; kt < NKT; ++kt) {
    __builtin_amdgcn_sched_barrier(0);
    if (kt < NKT - 1) { WAITV(6); } else { WAITV(0); }
    __builtin_amdgcn_s_barrier();
    CFENCE;

    const unsigned short* Ab = &SB[(kt % 3) * 24576];
    const unsigned short* Bb = Ab + 16384;
    const bool st = (kt + 2) < NKT;

    if (st) { stageA(kt + 2); stageB(kt + 2); }
    __builtin_amdgcn_sched_barrier(0);          // pin prefetch issue early

    // read all frags for both ks; compiler pipelines lgkmcnt under MFMAs
    bf16x8 af[2][4], bfv[2][4];
    #pragma unroll
    for (int ks = 0; ks < 2; ++ks) {
      const int kc = ks * 32 + (lane >> 4) * 8;
      #pragma unroll
      for (int fm = 0; fm < 4; ++fm) {
        int r = wm * 64 + fm * 16 + (lane & 15);
        af[ks][fm] = *reinterpret_cast<const bf16x8*>(&Ab[r * 64 + (kc ^ ((r & 7) << 3))]);
      }
      #pragma unroll
      for (int fn = 0; fn < 4; ++fn) {
        int r = wn * 64 + fn * 16 + (lane & 15);
        bfv[ks][fn] = *reinterpret_cast<const bf16x8*>(&Bb[r * 64 + (kc ^ ((r & 7) << 3))]);
      }
    }
    __builtin_amdgcn_s_setprio(1);
    #pragma unroll
    for (int ks = 0; ks < 2; ++ks)
      #pragma unroll
      for (int fm = 0; fm < 4; ++fm)
        #pragma unroll
        for (int fn = 0; fn < 4; ++fn)
          acc[fm][fn] = __builtin_amdgcn_mfma_f32_16x16x32_bf16(af[ks][fm], bfv[ks][fn], acc[fm][fn], 0, 0, 0);
    __builtin_amdgcn_s_setprio(0);
  }

  #pragma unroll
  for (int fm = 0; fm < 4; ++fm) {
    #pragma unroll
    for (int fn = 0; fn < 4; ++fn) {
      int col = n0 + wn * 64 + fn * 16 + (lane & 15);
      float bsv = bias[col];
      #pragma unroll
      for (int i = 0; i < 4; ++i) {
        int row = m0 + wm * 64 + fm * 16 + (lane >> 4) * 4 + i;
        float v = (acc[fm][fn][i] + bsv) * scale;
        ob[(size_t)row * Ncols + col] = f2bf(v);
      }
    }
  }
}

// ---------------- proj GEMM: ring-3, BM=128, unpinned body -----------------
// BM=128, BN=128, BK=64, 8 waves (2m x 4n), per-wave 64x32; LDS 96 KB.
__global__ __launch_bounds__(512)
void gemm_proj(const unsigned short* __restrict__ Ag,
               const unsigned short* __restrict__ Wg,
               const float* __restrict__ bias,
               float* __restrict__ fout) {
  __shared__ unsigned short SB[3 * 16384];

  const int tid  = threadIdx.x;
  const int lane = tid & 63;
  const int w    = tid >> 6;
  const int wm   = w >> 2, wn = w & 3;

  int bid = xcd_swz(blockIdx.x, gridDim.x);
  const int rt = bid / 6, ct = bid % 6;
  const int m0 = rt * 128, n0 = ct * 128;

  auto stageP = [&](int kt, const unsigned short* src, int base_row, int half) {
    const int kb = kt * 64;
    unsigned short* dst = &SB[(kt % 3) * 16384 + half * 8192];
    #pragma unroll
    for (int rnd = 0; rnd < 2; ++rnd) {
      int s    = rnd * 8 + w;
      int srow = s * 8 + (lane >> 3);
      int scol = ((lane & 7) * 8) ^ ((srow & 7) << 3);
      gl_lds16(&src[(size_t)(base_row + srow) * 768 + kb + scol], dst + s * 512);
    }
  };

  f32x4 acc[4][2] = {};

  stageP(0, Ag, m0, 0); stageP(0, Wg, n0, 1);
  stageP(1, Ag, m0, 0); stageP(1, Wg, n0, 1);

  for (int kt = 0; kt < NKT; ++kt) {
    __builtin_amdgcn_sched_barrier(0);
    if (kt < NKT - 1) { WAITV(4); } else { WAITV(0); }
    __builtin_amdgcn_s_barrier();
    CFENCE;

    const unsigned short* Ab = &SB[(kt % 3) * 16384];
    const unsigned short* Bb = Ab + 8192;
    const bool st = (kt + 2) < NKT;

    if (st) { stageP(kt + 2, Ag, m0, 0); stageP(kt + 2, Wg, n0, 1); }
    __builtin_amdgcn_sched_barrier(0);          // pin prefetch issue early

    bf16x8 af[2][4], bfv[2][2];
    #pragma unroll
    for (int ks = 0; ks < 2; ++ks) {
      const int kc = ks * 32 + (lane >> 4) * 8;
      #pragma unroll
      for (int fm = 0; fm < 4; ++fm) {
        int r = wm * 64 + fm * 16 + (lane & 15);
        af[ks][fm] = *reinterpret_cast<const bf16x8*>(&Ab[r * 64 + (kc ^ ((r & 7) << 3))]);
      }
      #pragma unroll
      for (int fn = 0; fn < 2; ++fn) {
        int r = wn * 32 + fn * 16 + (lane & 15);
        bfv[ks][fn] = *reinterpret_cast<const bf16x8*>(&Bb[r * 64 + (kc ^ ((r & 7) << 3))]);
      }
    }
    __builtin_amdgcn_s_setprio(1);
    #pragma unroll
    for (int ks = 0; ks < 2; ++ks)
      #pragma unroll
      for (int fm = 0; fm < 4; ++fm)
        #pragma unroll
        for (int fn = 0; fn < 2; ++fn)
          acc[fm][fn] = __builtin_amdgcn_mfma_f32_16x16x32_bf16(af[ks][fm], bfv[ks][fn], acc[fm][fn], 0, 0, 0);
    __builtin_amdgcn_s_setprio(0);
  }

  #pragma unroll
  for (int fm = 0; fm < 4; ++fm) {
    #pragma unroll
    for (int fn = 0; fn < 2; ++fn) {
      int col = n0 + wn * 32 + fn * 16 + (lane & 15);
      float bsv = bias[col];
      #pragma unroll
      for (int i = 0; i < 4; ++i) {
        int row = m0 + wm * 64 + fm * 16 + (lane >> 4) * 4 + i;
        float v = acc[fm][fn][i] + bsv;
        int bn = row >> 3, t = row & 7;
        int b  = bn / NTOK, n = bn - b * NTOK;
        fout[((1 + n) * 128 + b * 8 + t) * DIM + col] = v;
      }
    }
  }
}

// ---------------- attention: per (bn,h), t=8, hd=64 ----------------
__global__ __launch_bounds__(256)
void attn_kernel(const unsigned short* __restrict__ qb,
                 const unsigned short* __restrict__ kvb,
                 unsigned short* __restrict__ ob) {
  __shared__ __align__(16) float lds[4][3][8][68];
  const int tid  = threadIdx.x;
  const int lane = tid & 63;
  const int w    = tid >> 6;
  const int wid  = blockIdx.x * 4 + w;
  const int bn   = wid / HEADS;
  const int h    = wid - bn * HEADS;

  const int t  = lane >> 3;
  const int d0 = (lane & 7) * 8;
  const int qoff = (bn * 8 + t) * DIM + h * 64 + d0;
  const int koff = (bn * 8 + t) * (2 * DIM) + h * 64 + d0;

  u16x8 q8 = *reinterpret_cast<const u16x8*>(&qb[qoff]);
  u16x8 k8 = *reinterpret_cast<const u16x8*>(&kvb[koff]);
  u16x8 v8 = *reinterpret_cast<const u16x8*>(&kvb[koff + DIM]);
  f32x4 qa, qc, ka, kc, va, vc;
  #pragma unroll
  for (int e = 0; e < 4; ++e) {
    qa[e] = bf2f(q8[e]); qc[e] = bf2f(q8[e + 4]);
    ka[e] = bf2f(k8[e]); kc[e] = bf2f(k8[e + 4]);
    va[e] = bf2f(v8[e]); vc[e] = bf2f(v8[e + 4]);
  }
  *reinterpret_cast<f32x4*>(&lds[w][0][t][d0])     = qa;
  *reinterpret_cast<f32x4*>(&lds[w][0][t][d0 + 4]) = qc;
  *reinterpret_cast<f32x4*>(&lds[w][1][t][d0])     = ka;
  *reinterpret_cast<f32x4*>(&lds[w][1][t][d0 + 4]) = kc;
  *reinterpret_cast<f32x4*>(&lds[w][2][t][d0])     = va;
  *reinterpret_cast<f32x4*>(&lds[w][2][t][d0 + 4]) = vc;
  __syncthreads();

  const int i = lane >> 3, j = lane & 7;
  const f32x4* qi = reinterpret_cast<const f32x4*>(&lds[w][0][i][0]);
  const f32x4* kj = reinterpret_cast<const f32x4*>(&lds[w][1][j][0]);
  float s = 0.f;
  #pragma unroll
  for (int c = 0; c < 16; ++c) {
    f32x4 a = qi[c], b = kj[c];
    s += a[0] * b[0] + a[1] * b[1] + a[2] * b[2] + a[3] * b[3];
  }
  float m = s;
  m = fmaxf(m, __shfl_xor(m, 1));
  m = fmaxf(m, __shfl_xor(m, 2));
  m = fmaxf(m, __shfl_xor(m, 4));
  float e = __expf(s - m);
  float sum = e;
  sum += __shfl_xor(sum, 1);
  sum += __shfl_xor(sum, 2);
  sum += __shfl_xor(sum, 4);
  float p = e / sum;

  float o[8] = {};
  #pragma unroll
  for (int jj = 0; jj < 8; ++jj) {
    float pj = __shfl(p, (lane & 56) | jj);
    const f32x4* vj = reinterpret_cast<const f32x4*>(&lds[w][2][jj][d0]);
    f32x4 v0 = vj[0], v1 = vj[1];
    o[0] += pj * v0[0]; o[1] += pj * v0[1]; o[2] += pj * v0[2]; o[3] += pj * v0[3];
    o[4] += pj * v1[0]; o[5] += pj * v1[1]; o[6] += pj * v1[2]; o[7] += pj * v1[3];
  }
  u16x8 os;
  #pragma unroll
  for (int e2 = 0; e2 < 8; ++e2) os[e2] = f2bf(o[e2]);
  *reinterpret_cast<u16x8*>(&ob[qoff]) = os;
}

// ---------------- launch ----------------
extern "C" void kernel_launch(void* const* d_in, const int* in_sizes, int n_in,
                              void* d_out, int out_size, void* d_ws, size_t ws_size,
                              hipStream_t stream) {
  const float* s_x       = (const float*)d_in[0];
  const float* t_x       = (const float*)d_in[1];
  const float* clip_pos  = (const float*)d_in[2];
  const float* vmae_pos  = (const float*)d_in[3];
  const float* Wq        = (const float*)d_in[4];
  const float* q_bias    = (const float*)d_in[5];
  const float* Wkv       = (const float*)d_in[6];
  const float* kv_bias   = (const float*)d_in[7];
  const float* Wproj     = (const float*)d_in[8];
  const float* proj_bias = (const float*)d_in[9];
  float* out = (float*)d_out;

  char* ws = (char*)d_ws;
  unsigned short* w_bf = (unsigned short*)ws;                    // 4,718,592 B
  const size_t ABUF = 38535168, KVB = 77070336, WB = 4718592;
  const bool merged = ws_size >= (WB + 3 * ABUF + KVB);

  const unsigned short* wq_bf  = w_bf;
  const unsigned short* wkv_bf = w_bf + 589824;
  const unsigned short* wpj_bf = w_bf + 1769472;

  const int prep_blocks = (MROWS * 96 + 255) / 256;   // 9408

  wprep_kernel<<<dim3((589824 + 255) / 256), dim3(256), 0, stream>>>(Wq, Wkv, Wproj, w_bf);
  cls_kernel<<<dim3(96), dim3(256), 0, stream>>>(s_x, out);

  if (merged) {
    unsigned short* As    = (unsigned short*)(ws + WB);
    unsigned short* At    = (unsigned short*)(ws + WB + ABUF);
    unsigned short* q_bf  = (unsigned short*)(ws + WB + 2 * ABUF);
    unsigned short* kv_bf = (unsigned short*)(ws + WB + 3 * ABUF);
    aprep2_kernel<<<dim3(prep_blocks, 2), dim3(256), 0, stream>>>(
        s_x, t_x, clip_pos, vmae_pos, As, At, 0);
    gemm8<<<dim3(1764), dim3(512), 0, stream>>>(As, At, wq_bf, wkv_bf, q_bias, kv_bias,
                                                q_bf, kv_bf, 0);
    attn_kernel<<<dim3(9408), dim3(256), 0, stream>>>(q_bf, kv_bf, As);
    gemm_proj<<<dim3(1176), dim3(512), 0, stream>>>(As, wpj_bf, proj_bias, out);
  } else {
    unsigned short* buf1  = (unsigned short*)(ws + WB);
    unsigned short* q_bf  = (unsigned short*)(ws + WB + ABUF);
    unsigned short* kv_bf = (unsigned short*)(ws + WB + 2 * ABUF);
    aprep2_kernel<<<dim3(prep_blocks, 1), dim3(256), 0, stream>>>(
        s_x, t_x, clip_pos, vmae_pos, buf1, buf1, 0);          // y=0: s_x path
    gemm8<<<dim3(588), dim3(512), 0, stream>>>(buf1, buf1, wq_bf, wkv_bf, q_bias, kv_bias,
                                               q_bf, kv_bf, 0);
    aprep2_kernel<<<dim3(prep_blocks, 1), dim3(256), 0, stream>>>(
        s_x, t_x, clip_pos, vmae_pos, buf1, buf1, 1);          // ybase=1: t_x path
    gemm8<<<dim3(1176), dim3(512), 0, stream>>>(buf1, buf1, wq_bf, wkv_bf, q_bias, kv_bias,
                                                q_bf, kv_bf, 588);
    attn_kernel<<<dim3(9408), dim3(256), 0, stream>>>(q_bf, kv_bf, buf1);
    gemm_proj<<<dim3(1176), dim3(512), 0, stream>>>(buf1, wpj_bf, proj_bias, out);
  }
}

// Round 9
// 201.104 us; speedup vs baseline: 1.0613x; 1.0613x over previous
//
#include <hip/hip_runtime.h>
#include <stdint.h>

// ---------------- constants ----------------
#define DIM   768
#define NTOK  196
#define TT    8
#define MROWS 25088      // 3136 * 8
#define HEADS 12
#define NKT   12         // 768 / 64 K-tiles

typedef __bf16 bf16x8 __attribute__((ext_vector_type(8)));
typedef float  f32x4  __attribute__((ext_vector_type(4)));
typedef unsigned short u16x4 __attribute__((ext_vector_type(4)));
typedef unsigned short u16x8 __attribute__((ext_vector_type(8)));

typedef __attribute__((address_space(1))) const void GAS;
typedef __attribute__((address_space(3))) void LAS;

__device__ inline unsigned short f2bf(float f) {
  uint32_t u = __builtin_bit_cast(uint32_t, f);
  u += 0x7FFFu + ((u >> 16) & 1u);          // RNE
  return (unsigned short)(u >> 16);
}
__device__ inline float bf2f(unsigned short s) {
  uint32_t u = ((uint32_t)s) << 16;
  return __builtin_bit_cast(float, u);
}
__device__ inline void gl_lds16(const unsigned short* g, unsigned short* l) {
  __builtin_amdgcn_global_load_lds((GAS*)g, (LAS*)l, 16, 0, 0);
}
__device__ inline int xcd_swz(int orig, int nwg) {   // bijective (m204)
  int xcd = orig & 7, loc = orig >> 3;
  int q = nwg >> 3, r = nwg & 7;
  int base = (xcd < r) ? xcd * (q + 1) : r * (q + 1) + (xcd - r) * q;
  return base + loc;
}

// ---------------- merged prep: wprep + cls + aprep(s_x) + aprep(t_x) -------
// block ranges: [0,2304) wprep | [2304,2400) cls | [2400,11808) aprep-s |
//               [11808,21216) aprep-t.  Grid may be truncated (fallback).
__global__ __launch_bounds__(256)
void prep_all(const float* __restrict__ wq, const float* __restrict__ wkv,
              const float* __restrict__ wproj, unsigned short* __restrict__ w_bf,
              const float* __restrict__ s_x, const float* __restrict__ t_x,
              const float* __restrict__ clip, const float* __restrict__ vmae,
              unsigned short* __restrict__ As, unsigned short* __restrict__ At,
              float* __restrict__ cls_out, int bbase) {
  const int bx = blockIdx.x + bbase;
  if (bx < 2304) {
    int idx4 = bx * 256 + threadIdx.x;          // 2304*256 = 589824 exactly
    int e = idx4 * 4;
    const float* src; int off;
    if (e < 589824)        { src = wq;    off = e; }
    else if (e < 1769472)  { src = wkv;   off = e - 589824; }
    else                   { src = wproj; off = e - 1769472; }
    f32x4 v = *reinterpret_cast<const f32x4*>(&src[off]);
    u16x4 o;
    o[0] = f2bf(v[0]); o[1] = f2bf(v[1]); o[2] = f2bf(v[2]); o[3] = f2bf(v[3]);
    *reinterpret_cast<u16x4*>(&w_bf[e]) = o;
  } else if (bx < 2400) {
    int i4 = (bx - 2304) * 256 + threadIdx.x;   // 96*256 = 128*768/4 exactly
    reinterpret_cast<f32x4*>(cls_out)[i4] = reinterpret_cast<const f32x4*>(s_x)[i4];
  } else {
    const bool isS = bx < 11808;
    int idx = (bx - (isS ? 2400 : 11808)) * 256 + threadIdx.x;  // 9408*256 = MROWS*96
    int m  = idx / 96;
    int c8 = (idx - m * 96) * 8;
    int bn = m >> 3, t = m & 7;
    int b  = bn / NTOK, n = bn - b * NTOK;
    const float* src; const float* tp; unsigned short* dst; int srow;
    if (isS) { srow = (1 + n) * 128 + b * 8 + t;      src = s_x; tp = clip; dst = As; }
    else     { srow = b * (TT * NTOK) + t * NTOK + n; src = t_x; tp = vmae; dst = At; }
    const float* sp = &src[srow * DIM + c8];
    const float* pp = &tp[t * DIM + c8];
    f32x4 a0 = reinterpret_cast<const f32x4*>(sp)[0];
    f32x4 a1 = reinterpret_cast<const f32x4*>(sp)[1];
    f32x4 p0 = reinterpret_cast<const f32x4*>(pp)[0];
    f32x4 p1 = reinterpret_cast<const f32x4*>(pp)[1];
    a0 += p0; a1 += p1;
    u16x8 o;
    o[0] = f2bf(a0[0]); o[1] = f2bf(a0[1]); o[2] = f2bf(a0[2]); o[3] = f2bf(a0[3]);
    o[4] = f2bf(a1[0]); o[5] = f2bf(a1[1]); o[6] = f2bf(a1[2]); o[7] = f2bf(a1[3]);
    *reinterpret_cast<u16x8*>(&dst[m * DIM + c8]) = o;
  }
}

// ---------------- m97-style GEMM: 128x128, BK=64, 4 waves, 32 KB LDS -------
// Single-buffer 2-barrier loop; 4+ blocks/CU so cross-block TLP hides the
// stage drain (m114/m97: the measured-912TF plain-HIP structure).
// PROJ=0: merged Q/KV grid via bid0/nq (bid<nq*6: Q; else KV).
// PROJ=1: bf16 A x Wproj -> fp32 d_out with permuted rows.
template<int PROJ>
__global__ __launch_bounds__(256, 4)
void gemm97(const unsigned short* __restrict__ As,
            const unsigned short* __restrict__ At,
            const unsigned short* __restrict__ W0,
            const unsigned short* __restrict__ W1,
            const float* __restrict__ b0,
            const float* __restrict__ b1,
            unsigned short* __restrict__ out0,
            unsigned short* __restrict__ out1,
            float* __restrict__ fout, int bid0) {
  __shared__ unsigned short SA[8192];   // 128 x 64 bf16, 16 KB
  __shared__ unsigned short SBB[8192];

  const int tid  = threadIdx.x;
  const int lane = tid & 63;
  const int w    = tid >> 6;                 // 0..3
  const int wm   = w >> 1;                   // 0..1 row half
  const int wn   = w & 1;                    // 0..1 col half

  const int bid = xcd_swz(blockIdx.x, gridDim.x) + bid0;

  const unsigned short *Ag, *Wg;
  const float* bias;
  unsigned short* ob = nullptr;
  int rt, ct, Ncols = 768;
  float scale = 1.0f;
  if (PROJ == 0) {
    if (bid < 1176) { rt = bid / 6;  ct = bid % 6;  Ag = As; Wg = W0; bias = b0; ob = out0; Ncols = 768;  scale = 0.125f; }
    else { int b2 = bid - 1176; rt = b2 / 12; ct = b2 % 12; Ag = At; Wg = W1; bias = b1; ob = out1; Ncols = 1536; }
  } else {
    rt = bid / 6; ct = bid % 6; Ag = As; Wg = W0; bias = b0;
  }
  const int m0 = rt * 128;
  const int n0 = ct * 128;

  auto stA = [&](int kt) {
    #pragma unroll
    for (int rnd = 0; rnd < 4; ++rnd) {
      int srow = rnd * 32 + w * 8 + (lane >> 3);
      int scol = ((lane & 7) * 8) ^ ((srow & 7) << 3);
      gl_lds16(&Ag[(size_t)(m0 + srow) * 768 + kt * 64 + scol], &SA[(rnd * 4 + w) * 512]);
    }
  };
  auto stB = [&](int kt) {
    #pragma unroll
    for (int rnd = 0; rnd < 4; ++rnd) {
      int srow = rnd * 32 + w * 8 + (lane >> 3);
      int scol = ((lane & 7) * 8) ^ ((srow & 7) << 3);
      gl_lds16(&Wg[(size_t)(n0 + srow) * 768 + kt * 64 + scol], &SBB[(rnd * 4 + w) * 512]);
    }
  };

  f32x4 acc[4][4] = {};

  for (int kt = 0; kt < NKT; ++kt) {
    stA(kt); stB(kt);
    __syncthreads();                     // vmcnt drained: tile ready

    #pragma unroll
    for (int ks = 0; ks < 2; ++ks) {
      bf16x8 af[4], bfv[4];
      const int kc = ks * 32 + (lane >> 4) * 8;
      #pragma unroll
      for (int fm = 0; fm < 4; ++fm) {
        int r = wm * 64 + fm * 16 + (lane & 15);
        af[fm] = *reinterpret_cast<const bf16x8*>(&SA[r * 64 + (kc ^ ((r & 7) << 3))]);
      }
      #pragma unroll
      for (int fn = 0; fn < 4; ++fn) {
        int r = wn * 64 + fn * 16 + (lane & 15);
        bfv[fn] = *reinterpret_cast<const bf16x8*>(&SBB[r * 64 + (kc ^ ((r & 7) << 3))]);
      }
      __builtin_amdgcn_s_setprio(1);
      #pragma unroll
      for (int fm = 0; fm < 4; ++fm)
        #pragma unroll
        for (int fn = 0; fn < 4; ++fn)
          acc[fm][fn] = __builtin_amdgcn_mfma_f32_16x16x32_bf16(af[fm], bfv[fn], acc[fm][fn], 0, 0, 0);
      __builtin_amdgcn_s_setprio(0);
    }
    __syncthreads();                     // protect buffer before next stage
  }

  #pragma unroll
  for (int fm = 0; fm < 4; ++fm) {
    #pragma unroll
    for (int fn = 0; fn < 4; ++fn) {
      int col = n0 + wn * 64 + fn * 16 + (lane & 15);
      float bsv = bias[col];
      #pragma unroll
      for (int i = 0; i < 4; ++i) {
        int row = m0 + wm * 64 + fm * 16 + (lane >> 4) * 4 + i;
        float v = acc[fm][fn][i] + bsv;
        if (PROJ == 0) {
          v *= scale;
          ob[(size_t)row * Ncols + col] = f2bf(v);
        } else {
          int bn = row >> 3, t = row & 7;
          int b  = bn / NTOK, n = bn - b * NTOK;
          fout[((1 + n) * 128 + b * 8 + t) * DIM + col] = v;
        }
      }
    }
  }
}

// ---------------- attention: per (bn,h), t=8, hd=64 ----------------
__global__ __launch_bounds__(256)
void attn_kernel(const unsigned short* __restrict__ qb,
                 const unsigned short* __restrict__ kvb,
                 unsigned short* __restrict__ ob) {
  __shared__ __align__(16) float lds[4][3][8][68];
  const int tid  = threadIdx.x;
  const int lane = tid & 63;
  const int w    = tid >> 6;
  const int wid  = blockIdx.x * 4 + w;
  const int bn   = wid / HEADS;
  const int h    = wid - bn * HEADS;

  const int t  = lane >> 3;
  const int d0 = (lane & 7) * 8;
  const int qoff = (bn * 8 + t) * DIM + h * 64 + d0;
  const int koff = (bn * 8 + t) * (2 * DIM) + h * 64 + d0;

  u16x8 q8 = *reinterpret_cast<const u16x8*>(&qb[qoff]);
  u16x8 k8 = *reinterpret_cast<const u16x8*>(&kvb[koff]);
  u16x8 v8 = *reinterpret_cast<const u16x8*>(&kvb[koff + DIM]);
  f32x4 qa, qc, ka, kc, va, vc;
  #pragma unroll
  for (int e = 0; e < 4; ++e) {
    qa[e] = bf2f(q8[e]); qc[e] = bf2f(q8[e + 4]);
    ka[e] = bf2f(k8[e]); kc[e] = bf2f(k8[e + 4]);
    va[e] = bf2f(v8[e]); vc[e] = bf2f(v8[e + 4]);
  }
  *reinterpret_cast<f32x4*>(&lds[w][0][t][d0])     = qa;
  *reinterpret_cast<f32x4*>(&lds[w][0][t][d0 + 4]) = qc;
  *reinterpret_cast<f32x4*>(&lds[w][1][t][d0])     = ka;
  *reinterpret_cast<f32x4*>(&lds[w][1][t][d0 + 4]) = kc;
  *reinterpret_cast<f32x4*>(&lds[w][2][t][d0])     = va;
  *reinterpret_cast<f32x4*>(&lds[w][2][t][d0 + 4]) = vc;
  __syncthreads();

  const int i = lane >> 3, j = lane & 7;
  const f32x4* qi = reinterpret_cast<const f32x4*>(&lds[w][0][i][0]);
  const f32x4* kj = reinterpret_cast<const f32x4*>(&lds[w][1][j][0]);
  float s = 0.f;
  #pragma unroll
  for (int c = 0; c < 16; ++c) {
    f32x4 a = qi[c], b = kj[c];
    s += a[0] * b[0] + a[1] * b[1] + a[2] * b[2] + a[3] * b[3];
  }
  float m = s;
  m = fmaxf(m, __shfl_xor(m, 1));
  m = fmaxf(m, __shfl_xor(m, 2));
  m = fmaxf(m, __shfl_xor(m, 4));
  float e = __expf(s - m);
  float sum = e;
  sum += __shfl_xor(sum, 1);
  sum += __shfl_xor(sum, 2);
  sum += __shfl_xor(sum, 4);
  float p = e / sum;

  float o[8] = {};
  #pragma unroll
  for (int jj = 0; jj < 8; ++jj) {
    float pj = __shfl(p, (lane & 56) | jj);
    const f32x4* vj = reinterpret_cast<const f32x4*>(&lds[w][2][jj][d0]);
    f32x4 v0 = vj[0], v1 = vj[1];
    o[0] += pj * v0[0]; o[1] += pj * v0[1]; o[2] += pj * v0[2]; o[3] += pj * v0[3];
    o[4] += pj * v1[0]; o[5] += pj * v1[1]; o[6] += pj * v1[2]; o[7] += pj * v1[3];
  }
  u16x8 os;
  #pragma unroll
  for (int e2 = 0; e2 < 8; ++e2) os[e2] = f2bf(o[e2]);
  *reinterpret_cast<u16x8*>(&ob[qoff]) = os;
}

// ---------------- launch ----------------
extern "C" void kernel_launch(void* const* d_in, const int* in_sizes, int n_in,
                              void* d_out, int out_size, void* d_ws, size_t ws_size,
                              hipStream_t stream) {
  const float* s_x       = (const float*)d_in[0];
  const float* t_x       = (const float*)d_in[1];
  const float* clip_pos  = (const float*)d_in[2];
  const float* vmae_pos  = (const float*)d_in[3];
  const float* Wq        = (const float*)d_in[4];
  const float* q_bias    = (const float*)d_in[5];
  const float* Wkv       = (const float*)d_in[6];
  const float* kv_bias   = (const float*)d_in[7];
  const float* Wproj     = (const float*)d_in[8];
  const float* proj_bias = (const float*)d_in[9];
  float* out = (float*)d_out;

  char* ws = (char*)d_ws;
  unsigned short* w_bf = (unsigned short*)ws;                    // 4,718,592 B
  const size_t ABUF = 38535168, KVB = 77070336, WB = 4718592;
  const bool merged = ws_size >= (WB + 3 * ABUF + KVB);

  const unsigned short* wq_bf  = w_bf;
  const unsigned short* wkv_bf = w_bf + 589824;
  const unsigned short* wpj_bf = w_bf + 1769472;

  if (merged) {
    unsigned short* As    = (unsigned short*)(ws + WB);
    unsigned short* At    = (unsigned short*)(ws + WB + ABUF);
    unsigned short* q_bf  = (unsigned short*)(ws + WB + 2 * ABUF);
    unsigned short* kv_bf = (unsigned short*)(ws + WB + 3 * ABUF);
    // one prep dispatch: weights + CLS + both A-gathers (21216 blocks)
    prep_all<<<dim3(21216), dim3(256), 0, stream>>>(
        Wq, Wkv, Wproj, w_bf, s_x, t_x, clip_pos, vmae_pos, As, At, out, 0);
    // QKV: 196*6 (Q) + 196*12 (KV) = 3528 blocks of 128x128
    gemm97<0><<<dim3(3528), dim3(256), 0, stream>>>(
        As, At, wq_bf, wkv_bf, q_bias, kv_bias, q_bf, kv_bf, nullptr, 0);
    attn_kernel<<<dim3(9408), dim3(256), 0, stream>>>(q_bf, kv_bf, As);
    gemm97<1><<<dim3(1176), dim3(256), 0, stream>>>(
        As, nullptr, wpj_bf, nullptr, proj_bias, nullptr, nullptr, nullptr, out, 0);
  } else {
    // fallback: buf1 rotates (A_q -> A_kv -> attn-out); strictly sequential
    unsigned short* buf1  = (unsigned short*)(ws + WB);
    unsigned short* q_bf  = (unsigned short*)(ws + WB + ABUF);
    unsigned short* kv_bf = (unsigned short*)(ws + WB + 2 * ABUF);
    // wprep + cls + aprep-s -> buf1 (blocks [0, 11808))
    prep_all<<<dim3(11808), dim3(256), 0, stream>>>(
        Wq, Wkv, Wproj, w_bf, s_x, t_x, clip_pos, vmae_pos, buf1, buf1, out, 0);
    // Q GEMM only (bids [0,1176))
    gemm97<0><<<dim3(1176), dim3(256), 0, stream>>>(
        buf1, buf1, wq_bf, wkv_bf, q_bias, kv_bias, q_bf, kv_bf, nullptr, 0);
    // aprep-t -> buf1 (blocks [11808, 21216) via bbase)
    prep_all<<<dim3(9408), dim3(256), 0, stream>>>(
        Wq, Wkv, Wproj, w_bf, s_x, t_x, clip_pos, vmae_pos, buf1, buf1, out, 11808);
    // KV GEMM only (bids [1176, 3528) via bid0)
    gemm97<0><<<dim3(2352), dim3(256), 0, stream>>>(
        buf1, buf1, wq_bf, wkv_bf, q_bias, kv_bias, q_bf, kv_bf, nullptr, 1176);
    attn_kernel<<<dim3(9408), dim3(256), 0, stream>>>(q_bf, kv_bf, buf1);
    gemm97<1><<<dim3(1176), dim3(256), 0, stream>>>(
        buf1, nullptr, wpj_bf, nullptr, proj_bias, nullptr, nullptr, nullptr, out, 0);
  }
}